// Round 14
// baseline (431.418 us; speedup 1.0000x reference)
//
#include <hip/hip_runtime.h>

#define N_NODES 25000
#define N_EDGES 400000

// ---------------- fast transcendentals (fp32, ~2ulp) ----------------
__device__ __forceinline__ float fast_sigmoid(float x) {
    return __builtin_amdgcn_rcpf(1.0f + __expf(-x));
}
__device__ __forceinline__ float fast_tanh(float x) {
    return 1.0f - 2.0f * __builtin_amdgcn_rcpf(__expf(2.0f * x) + 1.0f);
}

// broadcast lane t of each 16-lane group (DS pipe; used only in the hoist):
#define BCAST16(x, t) __int_as_float(__builtin_amdgcn_ds_swizzle(__float_as_int(x), ((t) << 5) | 0x10))
// DPP row-rotate (VALU pipe, zero DS): lane j receives lane (j-N)&15 of its
// 16-lane row. dpp_ctrl row_ror:N = 0x120+N. row_mask/bank_mask full.
#define RORF(x, N) __int_as_float(__builtin_amdgcn_update_dpp(0, __float_as_int(x), 0x120 + (N), 0xF, 0xF, false))

// ---------------- K1: hidden0 = nf @ W_init + b_init ; copy; zero cnt/rcnt ---
__global__ void __launch_bounds__(256) k_init(
        const float* __restrict__ nf, const float* __restrict__ Wini,
        const float* __restrict__ bini,
        float* __restrict__ hidden0, float* __restrict__ hid,
        int* __restrict__ cnt, int* __restrict__ rcnt)
{
    int gtid = blockIdx.x * 256 + threadIdx.x;
    if (gtid <= N_NODES) { cnt[gtid] = 0; rcnt[gtid] = 0; }
    int node = gtid >> 4;
    int j = gtid & 15;
    if (node >= N_NODES) return;

    const float4* nf4 = (const float4*)(nf + node * 32);
    float acc = bini[j];
#pragma unroll
    for (int g = 0; g < 8; ++g) {
        float4 v = nf4[g];
        acc = fmaf(v.x, Wini[(g*4+0)*16 + j], acc);
        acc = fmaf(v.y, Wini[(g*4+1)*16 + j], acc);
        acc = fmaf(v.z, Wini[(g*4+2)*16 + j], acc);
        acc = fmaf(v.w, Wini[(g*4+3)*16 + j], acc);
    }
    hidden0[node*16 + j] = acc;
    hid[node*16 + j] = acc;
}

// ---------------- K2a: rank pass (histogram + within-bucket rank) ----------
__global__ void __launch_bounds__(256) k_rank(const int* __restrict__ send,
        const int* __restrict__ recv,
        int* __restrict__ cnt, int* __restrict__ rcnt,
        int* __restrict__ rank_s, int* __restrict__ rank_r)
{
    int e = blockIdx.x * 256 + threadIdx.x;
    if (e < N_EDGES) {
        rank_s[e] = atomicAdd(&cnt[send[e]], 1);
        rank_r[e] = atomicAdd(&rcnt[recv[e]], 1);
    }
}

// Two independent exclusive scans, one per block (LDS-staged, coalesced I/O).
#define SCAN_TOT 25600                      // 1024 * 25
__global__ void __launch_bounds__(1024) k_scan2(
        const int* __restrict__ cnt,  int* __restrict__ row_ptr,
        const int* __restrict__ rcnt, int* __restrict__ rrow_ptr,
        float* __restrict__ out)
{
    __shared__ int data[SCAN_TOT];          // 100 KB
    __shared__ int sums[1024];              // 4 KB
    int t = threadIdx.x;
    const int CH = 25;

    const int* SRC = blockIdx.x ? rcnt : cnt;
    int* DST = blockIdx.x ? rrow_ptr : row_ptr;

    for (int i = t; i < SCAN_TOT; i += 1024)
        data[i] = (i < N_NODES) ? SRC[i] : 0;
    __syncthreads();

    int base = t * CH;
    int s = 0;
#pragma unroll
    for (int i = 0; i < CH; ++i) s += data[base + i];
    sums[t] = s;
    __syncthreads();

    for (int off = 1; off < 1024; off <<= 1) {
        int add = (t >= off) ? sums[t - off] : 0;
        __syncthreads();
        sums[t] += add;
        __syncthreads();
    }
    int run = sums[t] - s;

#pragma unroll
    for (int i = 0; i < CH; ++i) {
        int v = data[base + i];
        data[base + i] = run;
        run += v;
    }
    __syncthreads();

    for (int i = t; i < N_NODES; i += 1024)
        DST[i] = data[i];
    if (t == 0) {
        if (blockIdx.x == 0) { row_ptr[N_NODES] = N_EDGES; out[0] = 0.0f; }
        else                 { rrow_ptr[N_NODES] = N_EDGES; }
    }
}

// ---------------- K2b: placement + feature permute, ZERO atomics ------------
__global__ void __launch_bounds__(256) k_place(const int* __restrict__ send,
        const int* __restrict__ recv,
        const int* __restrict__ rank_s, const int* __restrict__ rank_r,
        const int* __restrict__ row_ptr, const int* __restrict__ rrow_ptr,
        const float* __restrict__ ef, float* __restrict__ efp,
        int* __restrict__ rp)
{
    int e = blockIdx.x * 256 + threadIdx.x;
    if (e < N_EDGES) {
        int pos = row_ptr[send[e]] + rank_s[e];
        rp[pos] = rrow_ptr[recv[e]] + rank_r[e];
        const float4* src = (const float4*)(ef + (size_t)e * 16);
        float4* dst = (float4*)(efp + (size_t)pos * 16);
        float4 a = src[0], b = src[1], c = src[2], d = src[3];
        dst[0] = a; dst[1] = b; dst[2] = c; dst[3] = d;
    }
}

// ---------------- K3: 16 senders per block, efp staged through LDS,
// messages scatter-stored in RECEIVER order (rp) ----------
#define MCHUNK 512
#define MSG16(E0,E1,E2,E3) ( \
    ( fmaf((E0).w,q[3],  fmaf((E0).z,q[2],  fmaf((E0).y,q[1],  fmaf((E0).x,q[0],  qb)))) \
    + fmaf((E1).w,q[7],  fmaf((E1).z,q[6],  fmaf((E1).y,q[5],  fmaf((E1).x,q[4],  0.0f)))) ) \
  + ( fmaf((E2).w,q[11], fmaf((E2).z,q[10], fmaf((E2).y,q[9],  fmaf((E2).x,q[8],  0.0f)))) \
    + fmaf((E3).w,q[15], fmaf((E3).z,q[14], fmaf((E3).y,q[13], fmaf((E3).x,q[12], 0.0f)))) ) )

__global__ void __launch_bounds__(256) k_msg(
        const float* __restrict__ hid, const float* __restrict__ efp,
        const int* __restrict__ rp,
        const float* __restrict__ We, const float* __restrict__ be,
        const int* __restrict__ row_ptr,
        float* __restrict__ tmp)
{
    __shared__ float sef[MCHUNK * 16];          // 32 KB
    __shared__ int   srp[MCHUNK];               // 2 KB
    int tid = threadIdx.x;
    int grp = tid >> 4;
    int m   = tid & 15;
    int s   = blockIdx.x * 16 + grp;
    bool active = (s < N_NODES);
    int sc = active ? s : 0;

    int s0 = blockIdx.x * 16;
    int blk_beg = row_ptr[s0];
    int s1 = s0 + 16; if (s1 > N_NODES) s1 = N_NODES;
    int blk_end = row_ptr[s1];

    int beg = active ? row_ptr[s]     : 0;
    int end = active ? row_ptr[s + 1] : 0;

    float h[16];
    {
        const float4* h4 = (const float4*)(hid + sc*16);
        float4 a = h4[0], b = h4[1], c = h4[2], d = h4[3];
        h[0]=a.x; h[1]=a.y; h[2]=a.z;  h[3]=a.w;
        h[4]=b.x; h[5]=b.y; h[6]=b.z;  h[7]=b.w;
        h[8]=c.x; h[9]=c.y; h[10]=c.z; h[11]=c.w;
        h[12]=d.x; h[13]=d.y; h[14]=d.z; h[15]=d.w;
    }
    float q[16];
#pragma unroll
    for (int f = 0; f < 16; ++f) {
        const float4* wf = (const float4*)(We + f*256 + m*16);
        float4 a = wf[0], b = wf[1], c = wf[2], d = wf[3];
        float acc;
        acc  = a.x*h[0]  + a.y*h[1]  + a.z*h[2]  + a.w*h[3];
        acc += b.x*h[4]  + b.y*h[5]  + b.z*h[6]  + b.w*h[7];
        acc += c.x*h[8]  + c.y*h[9]  + c.z*h[10] + c.w*h[11];
        acc += d.x*h[12] + d.y*h[13] + d.z*h[14] + d.w*h[15];
        q[f] = acc;
    }
    float qb;
    {
        const float4* bf = (const float4*)(be + m*16);
        float4 a = bf[0], b = bf[1], c = bf[2], d = bf[3];
        qb  = a.x*h[0]  + a.y*h[1]  + a.z*h[2]  + a.w*h[3];
        qb += b.x*h[4]  + b.y*h[5]  + b.z*h[6]  + b.w*h[7];
        qb += c.x*h[8]  + c.y*h[9]  + c.z*h[10] + c.w*h[11];
        qb += d.x*h[12] + d.y*h[13] + d.z*h[14] + d.w*h[15];
    }

    for (int cbeg = blk_beg; cbeg < blk_end; cbeg += MCHUNK) {
        int cend = cbeg + MCHUNK; if (cend > blk_end) cend = blk_end;
        int nedge = cend - cbeg;
        int nfl = nedge * 4;
        __syncthreads();
        {
            const float4* gsrc = (const float4*)(efp + (size_t)cbeg * 16);
            float4* ldst = (float4*)sef;
            for (int i = tid; i < nfl; i += 256) ldst[i] = gsrc[i];
            for (int i = tid; i < nedge; i += 256) srp[i] = rp[cbeg + i];
        }
        __syncthreads();

        int lo = beg > cbeg ? beg : cbeg;
        int hi = end < cend ? end : cend;
        int i = lo;
        for (; i + 2 <= hi; i += 2) {
            const float4* l0 = (const float4*)(sef + (size_t)(i   - cbeg) * 16);
            const float4* l1 = (const float4*)(sef + (size_t)(i+1 - cbeg) * 16);
            float4 A0=l0[0], A1=l0[1], A2=l0[2], A3=l0[3];
            float4 B0=l1[0], B1=l1[1], B2=l1[2], B3=l1[3];
            int r0 = srp[i   - cbeg];
            int r1 = srp[i+1 - cbeg];
            float v0 = MSG16(A0, A1, A2, A3);
            float v1 = MSG16(B0, B1, B2, B3);
            tmp[(size_t)r0*16 + m] = v0;
            tmp[(size_t)r1*16 + m] = v1;
        }
        for (; i < hi; ++i) {
            const float4* l0 = (const float4*)(sef + (size_t)(i - cbeg) * 16);
            float4 A0=l0[0], A1=l0[1], A2=l0[2], A3=l0[3];
            int r0 = srp[i - cbeg];
            tmp[(size_t)r0*16 + m] = MSG16(A0, A1, A2, A3);
        }
    }
}

// ---------------- K4: STREAMING gather + GRU (T=32), DPP broadcast ----------
// The recurrence's 16 ds_swizzle/step (544 DS ops/thread) saturated the
// per-CU LDS pipe (one unit shared by 4 SIMDs): 24 waves x 544 x ~5cy ~ 27us
// floor -- why rounds 10/11/13 were null. Replace the per-step broadcasts
// with DPP row_ror:N (VALU pipe, zero DS): lane j receives lane (j-N)&15;
// weights pre-permuted to rotation order. DS ops: 544 -> 32 (x-hoist only).
// asm "+v" constraints pin the 48 weights + 32 x values in VGPRs so the
// allocator cannot rematerialize loads into the hot loop (round-13's 36-VGPR
// allocation reloaded weights every step).
__global__ void __launch_bounds__(256, 4) k_gru(
        const float* __restrict__ hid_in, const float* __restrict__ tmp,
        const int* __restrict__ rrow_ptr,
        const float* __restrict__ Wi, const float* __restrict__ Wh,
        const float* __restrict__ bi, const float* __restrict__ bh,
        float* __restrict__ hid_out)
{
    int gtid = blockIdx.x * 256 + threadIdx.x;
    int node = gtid >> 4;
    int j = gtid & 15;
    if (node >= N_NODES) return;

    float s0 = 0.0f, s1 = 0.0f, s2 = 0.0f, s3 = 0.0f;
    {
        int beg = rrow_ptr[node];
        int end = rrow_ptr[node + 1];
        const float* p = tmp + (size_t)beg * 16 + j;
        int d = end - beg;
        int i = 0;
        for (; i + 8 <= d; i += 8) {
            float a0 = p[(i+0)*16];
            float a1 = p[(i+1)*16];
            float a2 = p[(i+2)*16];
            float a3 = p[(i+3)*16];
            float a4 = p[(i+4)*16];
            float a5 = p[(i+5)*16];
            float a6 = p[(i+6)*16];
            float a7 = p[(i+7)*16];
            s0 += a0; s1 += a1; s2 += a2; s3 += a3;
            s0 += a4; s1 += a5; s2 += a6; s3 += a7;
        }
        for (; i < d; ++i) s0 += p[i*16];
    }
    float msg_own = (s0 + s1) + (s2 + s3);
    float h_own = hid_in[node*16 + j];

    // rotation-ordered weights: term N pairs with hn from lane (j-N)&15
    float Wz[16], Wr[16], Wc[16];
#pragma unroll
    for (int N = 0; N < 16; ++N) {
        int l = (j - N) & 15;
        Wz[N] = Wh[l*48 + j];
        Wr[N] = Wh[l*48 + 16 + j];
        Wc[N] = Wh[l*48 + 32 + j];
    }
#pragma unroll
    for (int N = 0; N < 16; ++N) {
        asm("" : "+v"(Wz[N]));
        asm("" : "+v"(Wr[N]));
        asm("" : "+v"(Wc[N]));
    }
    float Wiz = Wi[j], Wir = Wi[16+j], Wih = Wi[32+j];
    float cz   = bi[j] + bh[j];
    float cr   = bi[16+j] + bh[16+j];
    float bih_ = bi[32+j];
    float bhh_ = bh[32+j];

    // hoist all sequence-input broadcasts (32 DS ops total, off critical path)
    float x[32];
    x[0]  = BCAST16(h_own, 0);   x[1]  = BCAST16(h_own, 1);
    x[2]  = BCAST16(h_own, 2);   x[3]  = BCAST16(h_own, 3);
    x[4]  = BCAST16(h_own, 4);   x[5]  = BCAST16(h_own, 5);
    x[6]  = BCAST16(h_own, 6);   x[7]  = BCAST16(h_own, 7);
    x[8]  = BCAST16(h_own, 8);   x[9]  = BCAST16(h_own, 9);
    x[10] = BCAST16(h_own, 10);  x[11] = BCAST16(h_own, 11);
    x[12] = BCAST16(h_own, 12);  x[13] = BCAST16(h_own, 13);
    x[14] = BCAST16(h_own, 14);  x[15] = BCAST16(h_own, 15);
    x[16] = BCAST16(msg_own, 0);  x[17] = BCAST16(msg_own, 1);
    x[18] = BCAST16(msg_own, 2);  x[19] = BCAST16(msg_own, 3);
    x[20] = BCAST16(msg_own, 4);  x[21] = BCAST16(msg_own, 5);
    x[22] = BCAST16(msg_own, 6);  x[23] = BCAST16(msg_own, 7);
    x[24] = BCAST16(msg_own, 8);  x[25] = BCAST16(msg_own, 9);
    x[26] = BCAST16(msg_own, 10); x[27] = BCAST16(msg_own, 11);
    x[28] = BCAST16(msg_own, 12); x[29] = BCAST16(msg_own, 13);
    x[30] = BCAST16(msg_own, 14); x[31] = BCAST16(msg_own, 15);
#pragma unroll
    for (int t = 0; t < 32; ++t) { asm("" : "+v"(x[t])); }

    float hn = 0.0f;

#define STEPN(N) { float v = RORF(hn, N); \
        az = fmaf(v, Wz[N], az); ar = fmaf(v, Wr[N], ar); ac = fmaf(v, Wc[N], ac); }

#define GRUSTEP(XV) { \
        float xv = (XV); \
        float az = fmaf(xv, Wiz, cz); \
        float ar = fmaf(xv, Wir, cr); \
        float ac = bhh_; \
        az = fmaf(hn, Wz[0], az); \
        ar = fmaf(hn, Wr[0], ar); \
        ac = fmaf(hn, Wc[0], ac); \
        STEPN(1)  STEPN(2)  STEPN(3)  STEPN(4)  STEPN(5) \
        STEPN(6)  STEPN(7)  STEPN(8)  STEPN(9)  STEPN(10) \
        STEPN(11) STEPN(12) STEPN(13) STEPN(14) STEPN(15) \
        float z  = fast_sigmoid(az); \
        float r  = fast_sigmoid(ar); \
        float hc = fast_tanh(fmaf(xv, Wih, bih_) + r * ac); \
        hn = fmaf(z, hn - hc, hc); }

    GRUSTEP(x[0])  GRUSTEP(x[1])  GRUSTEP(x[2])  GRUSTEP(x[3])
    GRUSTEP(x[4])  GRUSTEP(x[5])  GRUSTEP(x[6])  GRUSTEP(x[7])
    GRUSTEP(x[8])  GRUSTEP(x[9])  GRUSTEP(x[10]) GRUSTEP(x[11])
    GRUSTEP(x[12]) GRUSTEP(x[13]) GRUSTEP(x[14]) GRUSTEP(x[15])
    GRUSTEP(x[16]) GRUSTEP(x[17]) GRUSTEP(x[18]) GRUSTEP(x[19])
    GRUSTEP(x[20]) GRUSTEP(x[21]) GRUSTEP(x[22]) GRUSTEP(x[23])
    GRUSTEP(x[24]) GRUSTEP(x[25]) GRUSTEP(x[26]) GRUSTEP(x[27])
    GRUSTEP(x[28]) GRUSTEP(x[29]) GRUSTEP(x[30]) GRUSTEP(x[31])
#undef GRUSTEP
#undef STEPN

    hid_out[node*16 + j] = hn;
}

// ---------------- K5: readout ----------------
__global__ void __launch_bounds__(256) k_readout(
        const float* __restrict__ hid, const float* __restrict__ hid0,
        const float* __restrict__ Wri, const float* __restrict__ bri,
        const float* __restrict__ Wrj, const float* __restrict__ brj,
        float* __restrict__ out)
{
    int n = blockIdx.x * 256 + threadIdx.x;
    float val = 0.0f;
    if (n < N_NODES) {
        const float4* h4 = (const float4*)(hid + n * 16);
        const float4* g4 = (const float4*)(hid0 + n * 16);
        float iv = bri[0];
        float jv = brj[0];
#pragma unroll
        for (int g = 0; g < 4; ++g) {
            float4 h  = h4[g];
            float4 h0 = g4[g];
            iv = fmaf(h.x,  Wri[g*4+0], iv);  iv = fmaf(h.y,  Wri[g*4+1], iv);
            iv = fmaf(h.z,  Wri[g*4+2], iv);  iv = fmaf(h.w,  Wri[g*4+3], iv);
            iv = fmaf(h0.x, Wri[16+g*4+0], iv); iv = fmaf(h0.y, Wri[16+g*4+1], iv);
            iv = fmaf(h0.z, Wri[16+g*4+2], iv); iv = fmaf(h0.w, Wri[16+g*4+3], iv);
            jv = fmaf(h.x,  Wrj[g*4+0], jv);  jv = fmaf(h.y,  Wrj[g*4+1], jv);
            jv = fmaf(h.z,  Wrj[g*4+2], jv);  jv = fmaf(h.w,  Wrj[g*4+3], jv);
        }
        val = iv * jv;
    }
#pragma unroll
    for (int off = 32; off > 0; off >>= 1)
        val += __shfl_xor(val, off, 64);
    __shared__ float wsum[4];
    int w = threadIdx.x >> 6;
    if ((threadIdx.x & 63) == 0) wsum[w] = val;
    __syncthreads();
    if (threadIdx.x == 0)
        atomicAdd(out, wsum[0] + wsum[1] + wsum[2] + wsum[3]);
}

// ---------------- launch ----------------
extern "C" void kernel_launch(void* const* d_in, const int* in_sizes, int n_in,
                              void* d_out, int out_size, void* d_ws, size_t ws_size,
                              hipStream_t stream)
{
    const float* node_features = (const float*)d_in[0];
    const float* edge_features = (const float*)d_in[1];
    const float* W_init = (const float*)d_in[2];
    const float* b_init = (const float*)d_in[3];
    const float* W_edge = (const float*)d_in[4];
    const float* b_edge = (const float*)d_in[5];
    const float* Wi_gru = (const float*)d_in[6];
    const float* Wh_gru = (const float*)d_in[7];
    const float* bi_gru = (const float*)d_in[8];
    const float* bh_gru = (const float*)d_in[9];
    const float* W_ri = (const float*)d_in[10];
    const float* b_ri = (const float*)d_in[11];
    const float* W_rj = (const float*)d_in[12];
    const float* b_rj = (const float*)d_in[13];
    const int* receivers = (const int*)d_in[14];
    const int* senders   = (const int*)d_in[15];
    float* out = (float*)d_out;

    // workspace carve: floats then ints; ~62 MB total
    float* fb      = (float*)d_ws;
    float* hidden0 = fb;                 // 400000
    float* hidA    = fb + 400000;        // 400000
    float* hidB    = fb + 800000;        // 400000
    float* tmp     = fb + 1200000;       // 6400000 (E*16, RECEIVER-order msgs)
    float* efp     = fb + 7600000;       // 6400000 (E*16, sender-order feats)
    int* ib       = (int*)(fb + 14000000);
    int* cnt      = ib;                  // 25024
    int* row_ptr  = ib + 25024;          // 25024
    int* rcnt     = ib + 50048;          // 25024
    int* rrow_ptr = ib + 75072;          // 25024
    int* rp       = ib + 100096;         // 400000 (sender slot -> receiver slot)
    int* rank_s   = ib + 500096;         // 400000
    int* rank_r   = ib + 900096;         // 400000

    dim3 b256(256);
    int grid_n16 = (N_NODES * 16 + 255) / 256;   // 1563
    int grid_e   = (N_EDGES + 255) / 256;        // 1563
    int grid_n   = (N_NODES + 255) / 256;        // 98
    int grid_blk = (N_NODES + 15) / 16;          // 1563 (16 senders per block)

    k_init<<<grid_n16, b256, 0, stream>>>(node_features, W_init, b_init,
                                          hidden0, hidA, cnt, rcnt);
    k_rank<<<grid_e, b256, 0, stream>>>(senders, receivers, cnt, rcnt,
                                        rank_s, rank_r);
    k_scan2<<<2, 1024, 0, stream>>>(cnt, row_ptr, rcnt, rrow_ptr, out);
    k_place<<<grid_e, b256, 0, stream>>>(senders, receivers, rank_s, rank_r,
                                         row_ptr, rrow_ptr,
                                         edge_features, efp, rp);

    float* hin = hidA;
    float* hout = hidB;
    for (int it = 0; it < 3; ++it) {
        k_msg<<<grid_blk, b256, 0, stream>>>(hin, efp, rp,
                                             W_edge, b_edge, row_ptr, tmp);
        k_gru<<<grid_n16, b256, 0, stream>>>(hin, tmp, rrow_ptr,
                                             Wi_gru, Wh_gru, bi_gru, bh_gru, hout);
        float* t = hin; hin = hout; hout = t;
    }

    k_readout<<<grid_n, b256, 0, stream>>>(hin, hidden0, W_ri, b_ri, W_rj, b_rj, out);
}

// Round 15
// 379.137 us; speedup vs baseline: 1.1379x; 1.1379x over previous
//
#include <hip/hip_runtime.h>

#define N_NODES 25000
#define N_EDGES 400000

// ---------------- fast transcendentals (fp32, ~2ulp) ----------------
__device__ __forceinline__ float fast_sigmoid(float x) {
    return __builtin_amdgcn_rcpf(1.0f + __expf(-x));
}
__device__ __forceinline__ float fast_tanh(float x) {
    return 1.0f - 2.0f * __builtin_amdgcn_rcpf(__expf(2.0f * x) + 1.0f);
}

// lane j receives value from lane j^k within its 32-lane half (k<16 keeps it
// inside the 16-lane node group). BitMode offset = (xor<<10)|(or<<5)|and.
#define SWZF(x, k) __int_as_float(__builtin_amdgcn_ds_swizzle(__float_as_int(x), ((k) << 10) | 0x1F))
// broadcast lane t of each 16-lane group: src = (lane & 0x10) | t
#define BCAST16(x, t) __int_as_float(__builtin_amdgcn_ds_swizzle(__float_as_int(x), ((t) << 5) | 0x10))

// ---------------- shared GRU recurrence (r11 form: split-chain, inline
// swizzle broadcasts; DS co-issues with VALU so this is the proven optimum) --
#define STEPK2(k0, k1) { \
        float va = SWZF(hn, k0); float vb = SWZF(hn, k1); \
        az0 = fmaf(va, Wz[k0], az0); az1 = fmaf(vb, Wz[k1], az1); \
        ar0 = fmaf(va, Wr[k0], ar0); ar1 = fmaf(vb, Wr[k1], ar1); \
        ac0 = fmaf(va, Wc[k0], ac0); ac1 = fmaf(vb, Wc[k1], ac1); }

#define GRUSTEP(XV) { \
        float xv = (XV); \
        float v1 = SWZF(hn, 1); \
        float az0 = fmaf(xv, Wiz, cz); \
        float ar0 = fmaf(xv, Wir, cr); \
        float ac0 = bhh_; \
        az0 = fmaf(hn, Wz[0], az0); \
        ar0 = fmaf(hn, Wr[0], ar0); \
        ac0 = fmaf(hn, Wc[0], ac0); \
        float az1 = v1 * Wz[1]; \
        float ar1 = v1 * Wr[1]; \
        float ac1 = v1 * Wc[1]; \
        STEPK2(2,3)   STEPK2(4,5)   STEPK2(6,7) \
        STEPK2(8,9)   STEPK2(10,11) STEPK2(12,13) \
        STEPK2(14,15) \
        float z  = fast_sigmoid(az0 + az1); \
        float r  = fast_sigmoid(ar0 + ar1); \
        float hc = fast_tanh(fmaf(xv, Wih, bih_) + r * (ac0 + ac1)); \
        hn = fmaf(z, hn - hc, hc); }

__device__ __forceinline__ float gru32(float h_own, float msg_own, int j,
        const float* __restrict__ Wi, const float* __restrict__ Wh,
        const float* __restrict__ bi, const float* __restrict__ bh)
{
    float Wz[16], Wr[16], Wc[16];
#pragma unroll
    for (int k = 0; k < 16; ++k) {
        int l = j ^ k;
        Wz[k] = Wh[l*48 + j];
        Wr[k] = Wh[l*48 + 16 + j];
        Wc[k] = Wh[l*48 + 32 + j];
    }
    float Wiz = Wi[j], Wir = Wi[16+j], Wih = Wi[32+j];
    float cz   = bi[j] + bh[j];
    float cr   = bi[16+j] + bh[16+j];
    float bih_ = bi[32+j];
    float bhh_ = bh[32+j];

    float hn = 0.0f;
    GRUSTEP(BCAST16(h_own, 0))  GRUSTEP(BCAST16(h_own, 1))
    GRUSTEP(BCAST16(h_own, 2))  GRUSTEP(BCAST16(h_own, 3))
    GRUSTEP(BCAST16(h_own, 4))  GRUSTEP(BCAST16(h_own, 5))
    GRUSTEP(BCAST16(h_own, 6))  GRUSTEP(BCAST16(h_own, 7))
    GRUSTEP(BCAST16(h_own, 8))  GRUSTEP(BCAST16(h_own, 9))
    GRUSTEP(BCAST16(h_own, 10)) GRUSTEP(BCAST16(h_own, 11))
    GRUSTEP(BCAST16(h_own, 12)) GRUSTEP(BCAST16(h_own, 13))
    GRUSTEP(BCAST16(h_own, 14)) GRUSTEP(BCAST16(h_own, 15))
    GRUSTEP(BCAST16(msg_own, 0))  GRUSTEP(BCAST16(msg_own, 1))
    GRUSTEP(BCAST16(msg_own, 2))  GRUSTEP(BCAST16(msg_own, 3))
    GRUSTEP(BCAST16(msg_own, 4))  GRUSTEP(BCAST16(msg_own, 5))
    GRUSTEP(BCAST16(msg_own, 6))  GRUSTEP(BCAST16(msg_own, 7))
    GRUSTEP(BCAST16(msg_own, 8))  GRUSTEP(BCAST16(msg_own, 9))
    GRUSTEP(BCAST16(msg_own, 10)) GRUSTEP(BCAST16(msg_own, 11))
    GRUSTEP(BCAST16(msg_own, 12)) GRUSTEP(BCAST16(msg_own, 13))
    GRUSTEP(BCAST16(msg_own, 14)) GRUSTEP(BCAST16(msg_own, 15))
    return hn;
}

// streaming gather: node's in-edge messages are contiguous (receiver-CSR)
__device__ __forceinline__ float gather16(const float* __restrict__ tmp,
        int beg, int end, int j)
{
    const float* p = tmp + (size_t)beg * 16 + j;
    int d = end - beg;
    float s0 = 0.0f, s1 = 0.0f, s2 = 0.0f, s3 = 0.0f;
    int i = 0;
    for (; i + 8 <= d; i += 8) {
        float a0 = p[(i+0)*16];
        float a1 = p[(i+1)*16];
        float a2 = p[(i+2)*16];
        float a3 = p[(i+3)*16];
        float a4 = p[(i+4)*16];
        float a5 = p[(i+5)*16];
        float a6 = p[(i+6)*16];
        float a7 = p[(i+7)*16];
        s0 += a0; s1 += a1; s2 += a2; s3 += a3;
        s0 += a4; s1 += a5; s2 += a6; s3 += a7;
    }
    for (; i < d; ++i) s0 += p[i*16];
    return (s0 + s1) + (s2 + s3);
}

// ---------------- shared message phase: q from h[16], edges via LDS chunks --
#define MCHUNK 256
#define MSG16(E0,E1,E2,E3) ( \
    ( fmaf((E0).w,q[3],  fmaf((E0).z,q[2],  fmaf((E0).y,q[1],  fmaf((E0).x,q[0],  qb)))) \
    + fmaf((E1).w,q[7],  fmaf((E1).z,q[6],  fmaf((E1).y,q[5],  fmaf((E1).x,q[4],  0.0f)))) ) \
  + ( fmaf((E2).w,q[11], fmaf((E2).z,q[10], fmaf((E2).y,q[9],  fmaf((E2).x,q[8],  0.0f)))) \
    + fmaf((E3).w,q[15], fmaf((E3).z,q[14], fmaf((E3).y,q[13], fmaf((E3).x,q[12], 0.0f)))) ) )

__device__ __forceinline__ void msg_phase(const float* __restrict__ h, int m,
        int tid, int blk_first, int beg, int end,
        const float* __restrict__ efp, const int* __restrict__ rp,
        const float* __restrict__ We, const float* __restrict__ be,
        const int* __restrict__ row_ptr, float* __restrict__ tmp,
        float* __restrict__ sef, int* __restrict__ srp)
{
    float q[16];
#pragma unroll
    for (int f = 0; f < 16; ++f) {
        const float4* wf = (const float4*)(We + f*256 + m*16);
        float4 a = wf[0], b = wf[1], c = wf[2], d = wf[3];
        float acc;
        acc  = a.x*h[0]  + a.y*h[1]  + a.z*h[2]  + a.w*h[3];
        acc += b.x*h[4]  + b.y*h[5]  + b.z*h[6]  + b.w*h[7];
        acc += c.x*h[8]  + c.y*h[9]  + c.z*h[10] + c.w*h[11];
        acc += d.x*h[12] + d.y*h[13] + d.z*h[14] + d.w*h[15];
        q[f] = acc;
    }
    float qb;
    {
        const float4* bf = (const float4*)(be + m*16);
        float4 a = bf[0], b = bf[1], c = bf[2], d = bf[3];
        qb  = a.x*h[0]  + a.y*h[1]  + a.z*h[2]  + a.w*h[3];
        qb += b.x*h[4]  + b.y*h[5]  + b.z*h[6]  + b.w*h[7];
        qb += c.x*h[8]  + c.y*h[9]  + c.z*h[10] + c.w*h[11];
        qb += d.x*h[12] + d.y*h[13] + d.z*h[14] + d.w*h[15];
    }

    int blk_beg = row_ptr[blk_first];
    int s1 = blk_first + 16; if (s1 > N_NODES) s1 = N_NODES;
    int blk_end = row_ptr[s1];

    for (int cbeg = blk_beg; cbeg < blk_end; cbeg += MCHUNK) {
        int cend = cbeg + MCHUNK; if (cend > blk_end) cend = blk_end;
        int nedge = cend - cbeg;
        int nfl = nedge * 4;
        __syncthreads();
        {
            const float4* gsrc = (const float4*)(efp + (size_t)cbeg * 16);
            float4* ldst = (float4*)sef;
            for (int i = tid; i < nfl; i += 256) ldst[i] = gsrc[i];
            for (int i = tid; i < nedge; i += 256) srp[i] = rp[cbeg + i];
        }
        __syncthreads();

        int lo = beg > cbeg ? beg : cbeg;
        int hi = end < cend ? end : cend;
        int i = lo;
        for (; i + 2 <= hi; i += 2) {
            const float4* l0 = (const float4*)(sef + (size_t)(i   - cbeg) * 16);
            const float4* l1 = (const float4*)(sef + (size_t)(i+1 - cbeg) * 16);
            float4 A0=l0[0], A1=l0[1], A2=l0[2], A3=l0[3];
            float4 B0=l1[0], B1=l1[1], B2=l1[2], B3=l1[3];
            int r0 = srp[i   - cbeg];
            int r1 = srp[i+1 - cbeg];
            float v0 = MSG16(A0, A1, A2, A3);
            float v1 = MSG16(B0, B1, B2, B3);
            tmp[(size_t)r0*16 + m] = v0;
            tmp[(size_t)r1*16 + m] = v1;
        }
        for (; i < hi; ++i) {
            const float4* l0 = (const float4*)(sef + (size_t)(i - cbeg) * 16);
            float4 A0=l0[0], A1=l0[1], A2=l0[2], A3=l0[3];
            int r0 = srp[i - cbeg];
            tmp[(size_t)r0*16 + m] = MSG16(A0, A1, A2, A3);
        }
    }
}

// ---------------- K1: hidden0 = nf @ W_init + b_init ; copy; zero cnt/rcnt ---
__global__ void __launch_bounds__(256) k_init(
        const float* __restrict__ nf, const float* __restrict__ Wini,
        const float* __restrict__ bini,
        float* __restrict__ hidden0, float* __restrict__ hid,
        int* __restrict__ cnt, int* __restrict__ rcnt)
{
    int gtid = blockIdx.x * 256 + threadIdx.x;
    if (gtid <= N_NODES) { cnt[gtid] = 0; rcnt[gtid] = 0; }
    int node = gtid >> 4;
    int j = gtid & 15;
    if (node >= N_NODES) return;

    const float4* nf4 = (const float4*)(nf + node * 32);
    float acc = bini[j];
#pragma unroll
    for (int g = 0; g < 8; ++g) {
        float4 v = nf4[g];
        acc = fmaf(v.x, Wini[(g*4+0)*16 + j], acc);
        acc = fmaf(v.y, Wini[(g*4+1)*16 + j], acc);
        acc = fmaf(v.z, Wini[(g*4+2)*16 + j], acc);
        acc = fmaf(v.w, Wini[(g*4+3)*16 + j], acc);
    }
    hidden0[node*16 + j] = acc;
    hid[node*16 + j] = acc;
}

// ---------------- K2a: rank pass (histogram + within-bucket rank) ----------
__global__ void __launch_bounds__(256) k_rank(const int* __restrict__ send,
        const int* __restrict__ recv,
        int* __restrict__ cnt, int* __restrict__ rcnt,
        int* __restrict__ rank_s, int* __restrict__ rank_r)
{
    int e = blockIdx.x * 256 + threadIdx.x;
    if (e < N_EDGES) {
        rank_s[e] = atomicAdd(&cnt[send[e]], 1);
        rank_r[e] = atomicAdd(&rcnt[recv[e]], 1);
    }
}

// Two independent exclusive scans, one per block (LDS-staged, coalesced I/O).
#define SCAN_TOT 25600                      // 1024 * 25
__global__ void __launch_bounds__(1024) k_scan2(
        const int* __restrict__ cnt,  int* __restrict__ row_ptr,
        const int* __restrict__ rcnt, int* __restrict__ rrow_ptr,
        float* __restrict__ out)
{
    __shared__ int data[SCAN_TOT];          // 100 KB
    __shared__ int sums[1024];              // 4 KB
    int t = threadIdx.x;
    const int CH = 25;

    const int* SRC = blockIdx.x ? rcnt : cnt;
    int* DST = blockIdx.x ? rrow_ptr : row_ptr;

    for (int i = t; i < SCAN_TOT; i += 1024)
        data[i] = (i < N_NODES) ? SRC[i] : 0;
    __syncthreads();

    int base = t * CH;
    int s = 0;
#pragma unroll
    for (int i = 0; i < CH; ++i) s += data[base + i];
    sums[t] = s;
    __syncthreads();

    for (int off = 1; off < 1024; off <<= 1) {
        int add = (t >= off) ? sums[t - off] : 0;
        __syncthreads();
        sums[t] += add;
        __syncthreads();
    }
    int run = sums[t] - s;

#pragma unroll
    for (int i = 0; i < CH; ++i) {
        int v = data[base + i];
        data[base + i] = run;
        run += v;
    }
    __syncthreads();

    for (int i = t; i < N_NODES; i += 1024)
        DST[i] = data[i];
    if (t == 0) {
        if (blockIdx.x == 0) { row_ptr[N_NODES] = N_EDGES; out[0] = 0.0f; }
        else                 { rrow_ptr[N_NODES] = N_EDGES; }
    }
}

// ---------------- K2b: placement + feature permute, ZERO atomics ------------
__global__ void __launch_bounds__(256) k_place(const int* __restrict__ send,
        const int* __restrict__ recv,
        const int* __restrict__ rank_s, const int* __restrict__ rank_r,
        const int* __restrict__ row_ptr, const int* __restrict__ rrow_ptr,
        const float* __restrict__ ef, float* __restrict__ efp,
        int* __restrict__ rp)
{
    int e = blockIdx.x * 256 + threadIdx.x;
    if (e < N_EDGES) {
        int pos = row_ptr[send[e]] + rank_s[e];
        rp[pos] = rrow_ptr[recv[e]] + rank_r[e];
        const float4* src = (const float4*)(ef + (size_t)e * 16);
        float4* dst = (float4*)(efp + (size_t)pos * 16);
        float4 a = src[0], b = src[1], c = src[2], d = src[3];
        dst[0] = a; dst[1] = b; dst[2] = c; dst[3] = d;
    }
}

// ---------------- K3: standalone message kernel (iteration 0) ---------------
__global__ void __launch_bounds__(256) k_msg(
        const float* __restrict__ hid, const float* __restrict__ efp,
        const int* __restrict__ rp,
        const float* __restrict__ We, const float* __restrict__ be,
        const int* __restrict__ row_ptr,
        float* __restrict__ tmp)
{
    __shared__ float sef[MCHUNK * 16];          // 16 KB
    __shared__ int   srp[MCHUNK];               // 1 KB
    int tid = threadIdx.x;
    int grp = tid >> 4;
    int m   = tid & 15;
    int s   = blockIdx.x * 16 + grp;
    bool active = (s < N_NODES);
    int sc = active ? s : 0;

    int beg = active ? row_ptr[s]     : 0;
    int end = active ? row_ptr[s + 1] : 0;

    float h[16];
    {
        const float4* h4 = (const float4*)(hid + sc*16);
        float4 a = h4[0], b = h4[1], c = h4[2], d = h4[3];
        h[0]=a.x; h[1]=a.y; h[2]=a.z;  h[3]=a.w;
        h[4]=b.x; h[5]=b.y; h[6]=b.z;  h[7]=b.w;
        h[8]=c.x; h[9]=c.y; h[10]=c.z; h[11]=c.w;
        h[12]=d.x; h[13]=d.y; h[14]=d.z; h[15]=d.w;
    }
    msg_phase(h, m, tid, blockIdx.x * 16, beg, end,
              efp, rp, We, be, row_ptr, tmp, sef, srp);
}

// ---------------- K4: standalone GRU kernel (final iteration) ---------------
__global__ void __launch_bounds__(256) k_gru(
        const float* __restrict__ hid_in, const float* __restrict__ tmp,
        const int* __restrict__ rrow_ptr,
        const float* __restrict__ Wi, const float* __restrict__ Wh,
        const float* __restrict__ bi, const float* __restrict__ bh,
        float* __restrict__ hid_out)
{
    int gtid = blockIdx.x * 256 + threadIdx.x;
    int node = gtid >> 4;
    int j = gtid & 15;
    if (node >= N_NODES) return;

    float msg_own = gather16(tmp, rrow_ptr[node], rrow_ptr[node + 1], j);
    float h_own = hid_in[node*16 + j];
    float hn = gru32(h_own, msg_own, j, Wi, Wh, bi, bh);
    hid_out[node*16 + j] = hn;
}

// ---------------- K6: FUSED gru(iter i) + msg(iter i+1) --------------------
// Sender s's messages depend only on s's OWN new hidden state, so GRU and the
// NEXT iteration's message compute compose per-node with no global sync.
// Phase A: gather(tmp_in)+GRU -> hn (write hid_out). Phase B: broadcast hn
// across the 16-lane group (16 literal swizzles), q-compute in-register,
// edge loop via LDS-staged efp -> tmp_out. Saves a launch + hid round-trip
// per iteration and gives cross-block pipe diversity (VALU-phase blocks
// overlap LDS/VMEM-phase blocks).
__global__ void __launch_bounds__(256) k_fused(
        const float* __restrict__ hid_in, const float* __restrict__ tmp_in,
        const int* __restrict__ rrow_ptr,
        const float* __restrict__ Wi, const float* __restrict__ Wh,
        const float* __restrict__ bi, const float* __restrict__ bh,
        float* __restrict__ hid_out,
        const float* __restrict__ efp, const int* __restrict__ rp,
        const float* __restrict__ We, const float* __restrict__ be,
        const int* __restrict__ row_ptr, float* __restrict__ tmp_out)
{
    __shared__ float sef[MCHUNK * 16];          // 16 KB
    __shared__ int   srp[MCHUNK];               // 1 KB
    int tid = threadIdx.x;
    int grp = tid >> 4;
    int j   = tid & 15;
    int node = blockIdx.x * 16 + grp;
    bool active = (node < N_NODES);
    int nc = active ? node : 0;

    // ---- Phase A: gather + GRU (no early return: barriers in Phase B) ----
    int gbeg = rrow_ptr[nc];
    int gend = active ? rrow_ptr[nc + 1] : gbeg;
    float msg_own = gather16(tmp_in, gbeg, gend, j);
    float h_own = hid_in[nc*16 + j];
    float hn = gru32(h_own, msg_own, j, Wi, Wh, bi, bh);
    if (active) hid_out[node*16 + j] = hn;

    // ---- Phase B: messages from fresh hn ----
    float h[16];
    h[0]  = BCAST16(hn, 0);   h[1]  = BCAST16(hn, 1);
    h[2]  = BCAST16(hn, 2);   h[3]  = BCAST16(hn, 3);
    h[4]  = BCAST16(hn, 4);   h[5]  = BCAST16(hn, 5);
    h[6]  = BCAST16(hn, 6);   h[7]  = BCAST16(hn, 7);
    h[8]  = BCAST16(hn, 8);   h[9]  = BCAST16(hn, 9);
    h[10] = BCAST16(hn, 10);  h[11] = BCAST16(hn, 11);
    h[12] = BCAST16(hn, 12);  h[13] = BCAST16(hn, 13);
    h[14] = BCAST16(hn, 14);  h[15] = BCAST16(hn, 15);

    int beg = active ? row_ptr[node]     : 0;
    int end = active ? row_ptr[node + 1] : 0;
    msg_phase(h, j, tid, blockIdx.x * 16, beg, end,
              efp, rp, We, be, row_ptr, tmp_out, sef, srp);
}

// ---------------- K5: readout ----------------
__global__ void __launch_bounds__(256) k_readout(
        const float* __restrict__ hid, const float* __restrict__ hid0,
        const float* __restrict__ Wri, const float* __restrict__ bri,
        const float* __restrict__ Wrj, const float* __restrict__ brj,
        float* __restrict__ out)
{
    int n = blockIdx.x * 256 + threadIdx.x;
    float val = 0.0f;
    if (n < N_NODES) {
        const float4* h4 = (const float4*)(hid + n * 16);
        const float4* g4 = (const float4*)(hid0 + n * 16);
        float iv = bri[0];
        float jv = brj[0];
#pragma unroll
        for (int g = 0; g < 4; ++g) {
            float4 h  = h4[g];
            float4 h0 = g4[g];
            iv = fmaf(h.x,  Wri[g*4+0], iv);  iv = fmaf(h.y,  Wri[g*4+1], iv);
            iv = fmaf(h.z,  Wri[g*4+2], iv);  iv = fmaf(h.w,  Wri[g*4+3], iv);
            iv = fmaf(h0.x, Wri[16+g*4+0], iv); iv = fmaf(h0.y, Wri[16+g*4+1], iv);
            iv = fmaf(h0.z, Wri[16+g*4+2], iv); iv = fmaf(h0.w, Wri[16+g*4+3], iv);
            jv = fmaf(h.x,  Wrj[g*4+0], jv);  jv = fmaf(h.y,  Wrj[g*4+1], jv);
            jv = fmaf(h.z,  Wrj[g*4+2], jv);  jv = fmaf(h.w,  Wrj[g*4+3], jv);
        }
        val = iv * jv;
    }
#pragma unroll
    for (int off = 32; off > 0; off >>= 1)
        val += __shfl_xor(val, off, 64);
    __shared__ float wsum[4];
    int w = threadIdx.x >> 6;
    if ((threadIdx.x & 63) == 0) wsum[w] = val;
    __syncthreads();
    if (threadIdx.x == 0)
        atomicAdd(out, wsum[0] + wsum[1] + wsum[2] + wsum[3]);
}

// ---------------- launch ----------------
extern "C" void kernel_launch(void* const* d_in, const int* in_sizes, int n_in,
                              void* d_out, int out_size, void* d_ws, size_t ws_size,
                              hipStream_t stream)
{
    const float* node_features = (const float*)d_in[0];
    const float* edge_features = (const float*)d_in[1];
    const float* W_init = (const float*)d_in[2];
    const float* b_init = (const float*)d_in[3];
    const float* W_edge = (const float*)d_in[4];
    const float* b_edge = (const float*)d_in[5];
    const float* Wi_gru = (const float*)d_in[6];
    const float* Wh_gru = (const float*)d_in[7];
    const float* bi_gru = (const float*)d_in[8];
    const float* bh_gru = (const float*)d_in[9];
    const float* W_ri = (const float*)d_in[10];
    const float* b_ri = (const float*)d_in[11];
    const float* W_rj = (const float*)d_in[12];
    const float* b_rj = (const float*)d_in[13];
    const int* receivers = (const int*)d_in[14];
    const int* senders   = (const int*)d_in[15];
    float* out = (float*)d_out;

    // workspace carve: floats then ints; ~88 MB total
    float* fb      = (float*)d_ws;
    float* hidden0 = fb;                 // 400000
    float* hidA    = fb + 400000;        // 400000
    float* hidB    = fb + 800000;        // 400000
    float* tmpA    = fb + 1200000;       // 6400000 (E*16, RECEIVER-order msgs)
    float* tmpB    = fb + 7600000;       // 6400000 (double buffer)
    float* efp     = fb + 14000000;      // 6400000 (E*16, sender-order feats)
    int* ib       = (int*)(fb + 20400000);
    int* cnt      = ib;                  // 25024
    int* row_ptr  = ib + 25024;          // 25024
    int* rcnt     = ib + 50048;          // 25024
    int* rrow_ptr = ib + 75072;          // 25024
    int* rp       = ib + 100096;         // 400000 (sender slot -> receiver slot)
    int* rank_s   = ib + 500096;         // 400000
    int* rank_r   = ib + 900096;         // 400000

    dim3 b256(256);
    int grid_n16 = (N_NODES * 16 + 255) / 256;   // 1563
    int grid_e   = (N_EDGES + 255) / 256;        // 1563
    int grid_n   = (N_NODES + 255) / 256;        // 98
    int grid_blk = (N_NODES + 15) / 16;          // 1563 (16 nodes per block)

    k_init<<<grid_n16, b256, 0, stream>>>(node_features, W_init, b_init,
                                          hidden0, hidA, cnt, rcnt);
    k_rank<<<grid_e, b256, 0, stream>>>(senders, receivers, cnt, rcnt,
                                        rank_s, rank_r);
    k_scan2<<<2, 1024, 0, stream>>>(cnt, row_ptr, rcnt, rrow_ptr, out);
    k_place<<<grid_e, b256, 0, stream>>>(senders, receivers, rank_s, rank_r,
                                         row_ptr, rrow_ptr,
                                         edge_features, efp, rp);

    // iter0 messages
    k_msg<<<grid_blk, b256, 0, stream>>>(hidA, efp, rp,
                                         W_edge, b_edge, row_ptr, tmpA);
    // gru0 + msg1
    k_fused<<<grid_blk, b256, 0, stream>>>(hidA, tmpA, rrow_ptr,
                                           Wi_gru, Wh_gru, bi_gru, bh_gru,
                                           hidB,
                                           efp, rp, W_edge, b_edge, row_ptr,
                                           tmpB);
    // gru1 + msg2
    k_fused<<<grid_blk, b256, 0, stream>>>(hidB, tmpB, rrow_ptr,
                                           Wi_gru, Wh_gru, bi_gru, bh_gru,
                                           hidA,
                                           efp, rp, W_edge, b_edge, row_ptr,
                                           tmpA);
    // gru2 (final)
    k_gru<<<grid_n16, b256, 0, stream>>>(hidA, tmpA, rrow_ptr,
                                         Wi_gru, Wh_gru, bi_gru, bh_gru, hidB);

    k_readout<<<grid_n, b256, 0, stream>>>(hidB, hidden0, W_ri, b_ri, W_rj, b_rj, out);
}

// Round 16
// 375.439 us; speedup vs baseline: 1.1491x; 1.0099x over previous
//
#include <hip/hip_runtime.h>

#define N_NODES 25000
#define N_EDGES 400000

// ---------------- fast transcendentals (fp32, ~2ulp) ----------------
__device__ __forceinline__ float fast_sigmoid(float x) {
    return __builtin_amdgcn_rcpf(1.0f + __expf(-x));
}
__device__ __forceinline__ float fast_tanh(float x) {
    return 1.0f - 2.0f * __builtin_amdgcn_rcpf(__expf(2.0f * x) + 1.0f);
}

// lane j receives value from lane j^k within its 32-lane half (k<16 keeps it
// inside the 16-lane node group). BitMode offset = (xor<<10)|(or<<5)|and.
#define SWZF(x, k) __int_as_float(__builtin_amdgcn_ds_swizzle(__float_as_int(x), ((k) << 10) | 0x1F))
// broadcast lane t of each 16-lane group: src = (lane & 0x10) | t
#define BCAST16(x, t) __int_as_float(__builtin_amdgcn_ds_swizzle(__float_as_int(x), ((t) << 5) | 0x10))

// ---------------- shared GRU recurrence (r11 form: split-chain, inline
// swizzle broadcasts; DS co-issues with VALU so this is the proven optimum) --
#define STEPK2(k0, k1) { \
        float va = SWZF(hn, k0); float vb = SWZF(hn, k1); \
        az0 = fmaf(va, Wz[k0], az0); az1 = fmaf(vb, Wz[k1], az1); \
        ar0 = fmaf(va, Wr[k0], ar0); ar1 = fmaf(vb, Wr[k1], ar1); \
        ac0 = fmaf(va, Wc[k0], ac0); ac1 = fmaf(vb, Wc[k1], ac1); }

#define GRUSTEP(XV) { \
        float xv = (XV); \
        float v1 = SWZF(hn, 1); \
        float az0 = fmaf(xv, Wiz, cz); \
        float ar0 = fmaf(xv, Wir, cr); \
        float ac0 = bhh_; \
        az0 = fmaf(hn, Wz[0], az0); \
        ar0 = fmaf(hn, Wr[0], ar0); \
        ac0 = fmaf(hn, Wc[0], ac0); \
        float az1 = v1 * Wz[1]; \
        float ar1 = v1 * Wr[1]; \
        float ac1 = v1 * Wc[1]; \
        STEPK2(2,3)   STEPK2(4,5)   STEPK2(6,7) \
        STEPK2(8,9)   STEPK2(10,11) STEPK2(12,13) \
        STEPK2(14,15) \
        float z  = fast_sigmoid(az0 + az1); \
        float r  = fast_sigmoid(ar0 + ar1); \
        float hc = fast_tanh(fmaf(xv, Wih, bih_) + r * (ac0 + ac1)); \
        hn = fmaf(z, hn - hc, hc); }

__device__ __forceinline__ float gru32(float h_own, float msg_own, int j,
        const float* __restrict__ Wi, const float* __restrict__ Wh,
        const float* __restrict__ bi, const float* __restrict__ bh)
{
    float Wz[16], Wr[16], Wc[16];
#pragma unroll
    for (int k = 0; k < 16; ++k) {
        int l = j ^ k;
        Wz[k] = Wh[l*48 + j];
        Wr[k] = Wh[l*48 + 16 + j];
        Wc[k] = Wh[l*48 + 32 + j];
    }
    float Wiz = Wi[j], Wir = Wi[16+j], Wih = Wi[32+j];
    float cz   = bi[j] + bh[j];
    float cr   = bi[16+j] + bh[16+j];
    float bih_ = bi[32+j];
    float bhh_ = bh[32+j];

    float hn = 0.0f;
    GRUSTEP(BCAST16(h_own, 0))  GRUSTEP(BCAST16(h_own, 1))
    GRUSTEP(BCAST16(h_own, 2))  GRUSTEP(BCAST16(h_own, 3))
    GRUSTEP(BCAST16(h_own, 4))  GRUSTEP(BCAST16(h_own, 5))
    GRUSTEP(BCAST16(h_own, 6))  GRUSTEP(BCAST16(h_own, 7))
    GRUSTEP(BCAST16(h_own, 8))  GRUSTEP(BCAST16(h_own, 9))
    GRUSTEP(BCAST16(h_own, 10)) GRUSTEP(BCAST16(h_own, 11))
    GRUSTEP(BCAST16(h_own, 12)) GRUSTEP(BCAST16(h_own, 13))
    GRUSTEP(BCAST16(h_own, 14)) GRUSTEP(BCAST16(h_own, 15))
    GRUSTEP(BCAST16(msg_own, 0))  GRUSTEP(BCAST16(msg_own, 1))
    GRUSTEP(BCAST16(msg_own, 2))  GRUSTEP(BCAST16(msg_own, 3))
    GRUSTEP(BCAST16(msg_own, 4))  GRUSTEP(BCAST16(msg_own, 5))
    GRUSTEP(BCAST16(msg_own, 6))  GRUSTEP(BCAST16(msg_own, 7))
    GRUSTEP(BCAST16(msg_own, 8))  GRUSTEP(BCAST16(msg_own, 9))
    GRUSTEP(BCAST16(msg_own, 10)) GRUSTEP(BCAST16(msg_own, 11))
    GRUSTEP(BCAST16(msg_own, 12)) GRUSTEP(BCAST16(msg_own, 13))
    GRUSTEP(BCAST16(msg_own, 14)) GRUSTEP(BCAST16(msg_own, 15))
    return hn;
}

// streaming gather: node's in-edge messages are contiguous (receiver-CSR)
__device__ __forceinline__ float gather16(const float* __restrict__ tmp,
        int beg, int end, int j)
{
    const float* p = tmp + (size_t)beg * 16 + j;
    int d = end - beg;
    float s0 = 0.0f, s1 = 0.0f, s2 = 0.0f, s3 = 0.0f;
    int i = 0;
    for (; i + 8 <= d; i += 8) {
        float a0 = p[(i+0)*16];
        float a1 = p[(i+1)*16];
        float a2 = p[(i+2)*16];
        float a3 = p[(i+3)*16];
        float a4 = p[(i+4)*16];
        float a5 = p[(i+5)*16];
        float a6 = p[(i+6)*16];
        float a7 = p[(i+7)*16];
        s0 += a0; s1 += a1; s2 += a2; s3 += a3;
        s0 += a4; s1 += a5; s2 += a6; s3 += a7;
    }
    for (; i < d; ++i) s0 += p[i*16];
    return (s0 + s1) + (s2 + s3);
}

// ---------------- shared message phase: q from h[16], edges via LDS chunks --
#define MCHUNK 256
#define MSG16(E0,E1,E2,E3) ( \
    ( fmaf((E0).w,q[3],  fmaf((E0).z,q[2],  fmaf((E0).y,q[1],  fmaf((E0).x,q[0],  qb)))) \
    + fmaf((E1).w,q[7],  fmaf((E1).z,q[6],  fmaf((E1).y,q[5],  fmaf((E1).x,q[4],  0.0f)))) ) \
  + ( fmaf((E2).w,q[11], fmaf((E2).z,q[10], fmaf((E2).y,q[9],  fmaf((E2).x,q[8],  0.0f)))) \
    + fmaf((E3).w,q[15], fmaf((E3).z,q[14], fmaf((E3).y,q[13], fmaf((E3).x,q[12], 0.0f)))) ) )

__device__ __forceinline__ void msg_phase(const float* __restrict__ h, int m,
        int tid, int blk_first, int beg, int end,
        const float* __restrict__ efp, const int* __restrict__ rp,
        const float* __restrict__ We, const float* __restrict__ be,
        const int* __restrict__ row_ptr, float* __restrict__ tmp,
        float* __restrict__ sef, int* __restrict__ srp)
{
    float q[16];
#pragma unroll
    for (int f = 0; f < 16; ++f) {
        const float4* wf = (const float4*)(We + f*256 + m*16);
        float4 a = wf[0], b = wf[1], c = wf[2], d = wf[3];
        float acc;
        acc  = a.x*h[0]  + a.y*h[1]  + a.z*h[2]  + a.w*h[3];
        acc += b.x*h[4]  + b.y*h[5]  + b.z*h[6]  + b.w*h[7];
        acc += c.x*h[8]  + c.y*h[9]  + c.z*h[10] + c.w*h[11];
        acc += d.x*h[12] + d.y*h[13] + d.z*h[14] + d.w*h[15];
        q[f] = acc;
    }
    float qb;
    {
        const float4* bf = (const float4*)(be + m*16);
        float4 a = bf[0], b = bf[1], c = bf[2], d = bf[3];
        qb  = a.x*h[0]  + a.y*h[1]  + a.z*h[2]  + a.w*h[3];
        qb += b.x*h[4]  + b.y*h[5]  + b.z*h[6]  + b.w*h[7];
        qb += c.x*h[8]  + c.y*h[9]  + c.z*h[10] + c.w*h[11];
        qb += d.x*h[12] + d.y*h[13] + d.z*h[14] + d.w*h[15];
    }

    int blk_beg = row_ptr[blk_first];
    int s1 = blk_first + 16; if (s1 > N_NODES) s1 = N_NODES;
    int blk_end = row_ptr[s1];

    for (int cbeg = blk_beg; cbeg < blk_end; cbeg += MCHUNK) {
        int cend = cbeg + MCHUNK; if (cend > blk_end) cend = blk_end;
        int nedge = cend - cbeg;
        int nfl = nedge * 4;
        __syncthreads();
        {
            const float4* gsrc = (const float4*)(efp + (size_t)cbeg * 16);
            float4* ldst = (float4*)sef;
            for (int i = tid; i < nfl; i += 256) ldst[i] = gsrc[i];
            for (int i = tid; i < nedge; i += 256) srp[i] = rp[cbeg + i];
        }
        __syncthreads();

        int lo = beg > cbeg ? beg : cbeg;
        int hi = end < cend ? end : cend;
        int i = lo;
        for (; i + 2 <= hi; i += 2) {
            const float4* l0 = (const float4*)(sef + (size_t)(i   - cbeg) * 16);
            const float4* l1 = (const float4*)(sef + (size_t)(i+1 - cbeg) * 16);
            float4 A0=l0[0], A1=l0[1], A2=l0[2], A3=l0[3];
            float4 B0=l1[0], B1=l1[1], B2=l1[2], B3=l1[3];
            int r0 = srp[i   - cbeg];
            int r1 = srp[i+1 - cbeg];
            float v0 = MSG16(A0, A1, A2, A3);
            float v1 = MSG16(B0, B1, B2, B3);
            tmp[(size_t)r0*16 + m] = v0;
            tmp[(size_t)r1*16 + m] = v1;
        }
        for (; i < hi; ++i) {
            const float4* l0 = (const float4*)(sef + (size_t)(i - cbeg) * 16);
            float4 A0=l0[0], A1=l0[1], A2=l0[2], A3=l0[3];
            int r0 = srp[i - cbeg];
            tmp[(size_t)r0*16 + m] = MSG16(A0, A1, A2, A3);
        }
    }
}

// ---------------- K2a: rank pass (histogram + within-bucket rank) ----------
__global__ void __launch_bounds__(256) k_rank(const int* __restrict__ send,
        const int* __restrict__ recv,
        int* __restrict__ cnt, int* __restrict__ rcnt,
        int* __restrict__ rank_s, int* __restrict__ rank_r)
{
    int e = blockIdx.x * 256 + threadIdx.x;
    if (e < N_EDGES) {
        rank_s[e] = atomicAdd(&cnt[send[e]], 1);
        rank_r[e] = atomicAdd(&rcnt[recv[e]], 1);
    }
}

// Two independent exclusive scans, one per block (LDS-staged, coalesced I/O).
#define SCAN_TOT 25600                      // 1024 * 25
__global__ void __launch_bounds__(1024) k_scan2(
        const int* __restrict__ cnt,  int* __restrict__ row_ptr,
        const int* __restrict__ rcnt, int* __restrict__ rrow_ptr,
        float* __restrict__ out)
{
    __shared__ int data[SCAN_TOT];          // 100 KB
    __shared__ int sums[1024];              // 4 KB
    int t = threadIdx.x;
    const int CH = 25;

    const int* SRC = blockIdx.x ? rcnt : cnt;
    int* DST = blockIdx.x ? rrow_ptr : row_ptr;

    for (int i = t; i < SCAN_TOT; i += 1024)
        data[i] = (i < N_NODES) ? SRC[i] : 0;
    __syncthreads();

    int base = t * CH;
    int s = 0;
#pragma unroll
    for (int i = 0; i < CH; ++i) s += data[base + i];
    sums[t] = s;
    __syncthreads();

    for (int off = 1; off < 1024; off <<= 1) {
        int add = (t >= off) ? sums[t - off] : 0;
        __syncthreads();
        sums[t] += add;
        __syncthreads();
    }
    int run = sums[t] - s;

#pragma unroll
    for (int i = 0; i < CH; ++i) {
        int v = data[base + i];
        data[base + i] = run;
        run += v;
    }
    __syncthreads();

    for (int i = t; i < N_NODES; i += 1024)
        DST[i] = data[i];
    if (t == 0) {
        if (blockIdx.x == 0) { row_ptr[N_NODES] = N_EDGES; out[0] = 0.0f; }
        else                 { rrow_ptr[N_NODES] = N_EDGES; }
    }
}

// ---------------- K2b: placement + feature permute, ZERO atomics ------------
__global__ void __launch_bounds__(256) k_place(const int* __restrict__ send,
        const int* __restrict__ recv,
        const int* __restrict__ rank_s, const int* __restrict__ rank_r,
        const int* __restrict__ row_ptr, const int* __restrict__ rrow_ptr,
        const float* __restrict__ ef, float* __restrict__ efp,
        int* __restrict__ rp)
{
    int e = blockIdx.x * 256 + threadIdx.x;
    if (e < N_EDGES) {
        int pos = row_ptr[send[e]] + rank_s[e];
        rp[pos] = rrow_ptr[recv[e]] + rank_r[e];
        const float4* src = (const float4*)(ef + (size_t)e * 16);
        float4* dst = (float4*)(efp + (size_t)pos * 16);
        float4 a = src[0], b = src[1], c = src[2], d = src[3];
        dst[0] = a; dst[1] = b; dst[2] = c; dst[3] = d;
    }
}

// ---------------- K3: FUSED init (hidden0 = nf@W_init+b) + msg(iter 0) ------
// Per node: 16 lanes compute dim j of hidden0, write hidden0/hid, broadcast
// across the group into h[16], then run the message phase directly -- saves
// the standalone k_init launch and the hid round-trip before msg0.
__global__ void __launch_bounds__(256) k_init_msg(
        const float* __restrict__ nf, const float* __restrict__ Wini,
        const float* __restrict__ bini,
        float* __restrict__ hidden0, float* __restrict__ hid,
        const float* __restrict__ efp, const int* __restrict__ rp,
        const float* __restrict__ We, const float* __restrict__ be,
        const int* __restrict__ row_ptr, float* __restrict__ tmp)
{
    __shared__ float sef[MCHUNK * 16];          // 16 KB
    __shared__ int   srp[MCHUNK];               // 1 KB
    int tid = threadIdx.x;
    int grp = tid >> 4;
    int j   = tid & 15;
    int node = blockIdx.x * 16 + grp;
    bool active = (node < N_NODES);
    int nc = active ? node : 0;

    const float4* nf4 = (const float4*)(nf + (size_t)nc * 32);
    float acc = bini[j];
#pragma unroll
    for (int g = 0; g < 8; ++g) {
        float4 v = nf4[g];
        acc = fmaf(v.x, Wini[(g*4+0)*16 + j], acc);
        acc = fmaf(v.y, Wini[(g*4+1)*16 + j], acc);
        acc = fmaf(v.z, Wini[(g*4+2)*16 + j], acc);
        acc = fmaf(v.w, Wini[(g*4+3)*16 + j], acc);
    }
    if (active) {
        hidden0[node*16 + j] = acc;
        hid[node*16 + j] = acc;
    }

    float h[16];
    h[0]  = BCAST16(acc, 0);   h[1]  = BCAST16(acc, 1);
    h[2]  = BCAST16(acc, 2);   h[3]  = BCAST16(acc, 3);
    h[4]  = BCAST16(acc, 4);   h[5]  = BCAST16(acc, 5);
    h[6]  = BCAST16(acc, 6);   h[7]  = BCAST16(acc, 7);
    h[8]  = BCAST16(acc, 8);   h[9]  = BCAST16(acc, 9);
    h[10] = BCAST16(acc, 10);  h[11] = BCAST16(acc, 11);
    h[12] = BCAST16(acc, 12);  h[13] = BCAST16(acc, 13);
    h[14] = BCAST16(acc, 14);  h[15] = BCAST16(acc, 15);

    int beg = active ? row_ptr[node]     : 0;
    int end = active ? row_ptr[node + 1] : 0;
    msg_phase(h, j, tid, blockIdx.x * 16, beg, end,
              efp, rp, We, be, row_ptr, tmp, sef, srp);
}

// ---------------- K6: FUSED gru(iter i) + msg(iter i+1) --------------------
__global__ void __launch_bounds__(256) k_fused(
        const float* __restrict__ hid_in, const float* __restrict__ tmp_in,
        const int* __restrict__ rrow_ptr,
        const float* __restrict__ Wi, const float* __restrict__ Wh,
        const float* __restrict__ bi, const float* __restrict__ bh,
        float* __restrict__ hid_out,
        const float* __restrict__ efp, const int* __restrict__ rp,
        const float* __restrict__ We, const float* __restrict__ be,
        const int* __restrict__ row_ptr, float* __restrict__ tmp_out)
{
    __shared__ float sef[MCHUNK * 16];          // 16 KB
    __shared__ int   srp[MCHUNK];               // 1 KB
    int tid = threadIdx.x;
    int grp = tid >> 4;
    int j   = tid & 15;
    int node = blockIdx.x * 16 + grp;
    bool active = (node < N_NODES);
    int nc = active ? node : 0;

    // ---- Phase A: gather + GRU (no early return: barriers in Phase B) ----
    int gbeg = rrow_ptr[nc];
    int gend = active ? rrow_ptr[nc + 1] : gbeg;
    float msg_own = gather16(tmp_in, gbeg, gend, j);
    float h_own = hid_in[nc*16 + j];
    float hn = gru32(h_own, msg_own, j, Wi, Wh, bi, bh);
    if (active) hid_out[node*16 + j] = hn;

    // ---- Phase B: messages from fresh hn ----
    float h[16];
    h[0]  = BCAST16(hn, 0);   h[1]  = BCAST16(hn, 1);
    h[2]  = BCAST16(hn, 2);   h[3]  = BCAST16(hn, 3);
    h[4]  = BCAST16(hn, 4);   h[5]  = BCAST16(hn, 5);
    h[6]  = BCAST16(hn, 6);   h[7]  = BCAST16(hn, 7);
    h[8]  = BCAST16(hn, 8);   h[9]  = BCAST16(hn, 9);
    h[10] = BCAST16(hn, 10);  h[11] = BCAST16(hn, 11);
    h[12] = BCAST16(hn, 12);  h[13] = BCAST16(hn, 13);
    h[14] = BCAST16(hn, 14);  h[15] = BCAST16(hn, 15);

    int beg = active ? row_ptr[node]     : 0;
    int end = active ? row_ptr[node + 1] : 0;
    msg_phase(h, j, tid, blockIdx.x * 16, beg, end,
              efp, rp, We, be, row_ptr, tmp_out, sef, srp);
}

// ---------------- K7: FUSED final gru + readout ------------------------------
// hn never round-trips to HBM: readout partials are computed in-register,
// reduced across the 16-lane group by swizzle butterfly, then one atomic per
// block. Deletes the k_readout dispatch + final hid write/read.
__global__ void __launch_bounds__(256) k_gru_red(
        const float* __restrict__ hid_in, const float* __restrict__ tmp,
        const int* __restrict__ rrow_ptr,
        const float* __restrict__ Wi, const float* __restrict__ Wh,
        const float* __restrict__ bi, const float* __restrict__ bh,
        const float* __restrict__ hid0,
        const float* __restrict__ Wri, const float* __restrict__ bri,
        const float* __restrict__ Wrj, const float* __restrict__ brj,
        float* __restrict__ out)
{
    int gtid = blockIdx.x * 256 + threadIdx.x;
    int node = gtid >> 4;
    int j = gtid & 15;
    bool active = (node < N_NODES);
    int nc = active ? node : 0;

    int gbeg = rrow_ptr[nc];
    int gend = active ? rrow_ptr[nc + 1] : gbeg;
    float msg_own = gather16(tmp, gbeg, gend, j);
    float h_own = hid_in[nc*16 + j];
    float hn = gru32(h_own, msg_own, j, Wi, Wh, bi, bh);

    float h0 = hid0[nc*16 + j];
    float pi = fmaf(hn, Wri[j], h0 * Wri[16 + j]);
    float pj = hn * Wrj[j];
    if (j == 0) { pi += bri[0]; pj += brj[0]; }
    // 16-lane butterfly: all lanes end with full sums
    pi += SWZF(pi, 1);  pj += SWZF(pj, 1);
    pi += SWZF(pi, 2);  pj += SWZF(pj, 2);
    pi += SWZF(pi, 4);  pj += SWZF(pj, 4);
    pi += SWZF(pi, 8);  pj += SWZF(pj, 8);

    float val = (active && j == 0) ? pi * pj : 0.0f;
#pragma unroll
    for (int off = 32; off > 0; off >>= 1)
        val += __shfl_xor(val, off, 64);
    __shared__ float wsum[4];
    int w = threadIdx.x >> 6;
    if ((threadIdx.x & 63) == 0) wsum[w] = val;
    __syncthreads();
    if (threadIdx.x == 0)
        atomicAdd(out, wsum[0] + wsum[1] + wsum[2] + wsum[3]);
}

// ---------------- launch ----------------
extern "C" void kernel_launch(void* const* d_in, const int* in_sizes, int n_in,
                              void* d_out, int out_size, void* d_ws, size_t ws_size,
                              hipStream_t stream)
{
    const float* node_features = (const float*)d_in[0];
    const float* edge_features = (const float*)d_in[1];
    const float* W_init = (const float*)d_in[2];
    const float* b_init = (const float*)d_in[3];
    const float* W_edge = (const float*)d_in[4];
    const float* b_edge = (const float*)d_in[5];
    const float* Wi_gru = (const float*)d_in[6];
    const float* Wh_gru = (const float*)d_in[7];
    const float* bi_gru = (const float*)d_in[8];
    const float* bh_gru = (const float*)d_in[9];
    const float* W_ri = (const float*)d_in[10];
    const float* b_ri = (const float*)d_in[11];
    const float* W_rj = (const float*)d_in[12];
    const float* b_rj = (const float*)d_in[13];
    const int* receivers = (const int*)d_in[14];
    const int* senders   = (const int*)d_in[15];
    float* out = (float*)d_out;

    // workspace carve: floats then ints; ~87 MB total
    float* fb      = (float*)d_ws;
    float* hidden0 = fb;                 // 400000
    float* hidA    = fb + 400000;        // 400000
    float* hidB    = fb + 800000;        // 400000
    float* tmpA    = fb + 1200000;       // 6400000 (E*16, RECEIVER-order msgs)
    float* tmpB    = fb + 7600000;       // 6400000 (double buffer)
    float* efp     = fb + 14000000;      // 6400000 (E*16, sender-order feats)
    int* ib       = (int*)(fb + 20400000);
    int* cnt      = ib;                  // 25024
    int* rcnt     = ib + 25024;          // 25024 (adjacent to cnt: one memset)
    int* row_ptr  = ib + 50048;          // 25024
    int* rrow_ptr = ib + 75072;          // 25024
    int* rp       = ib + 100096;         // 400000 (sender slot -> receiver slot)
    int* rank_s   = ib + 500096;         // 400000
    int* rank_r   = ib + 900096;         // 400000

    dim3 b256(256);
    int grid_e   = (N_EDGES + 255) / 256;        // 1563
    int grid_n16 = (N_NODES * 16 + 255) / 256;   // 1563
    int grid_blk = (N_NODES + 15) / 16;          // 1563 (16 nodes per block)

    hipMemsetAsync(cnt, 0, 2 * 25024 * sizeof(int), stream);
    k_rank<<<grid_e, b256, 0, stream>>>(senders, receivers, cnt, rcnt,
                                        rank_s, rank_r);
    k_scan2<<<2, 1024, 0, stream>>>(cnt, row_ptr, rcnt, rrow_ptr, out);
    k_place<<<grid_e, b256, 0, stream>>>(senders, receivers, rank_s, rank_r,
                                         row_ptr, rrow_ptr,
                                         edge_features, efp, rp);

    // init + iter0 messages
    k_init_msg<<<grid_blk, b256, 0, stream>>>(node_features, W_init, b_init,
                                              hidden0, hidA,
                                              efp, rp, W_edge, b_edge, row_ptr,
                                              tmpA);
    // gru0 + msg1
    k_fused<<<grid_blk, b256, 0, stream>>>(hidA, tmpA, rrow_ptr,
                                           Wi_gru, Wh_gru, bi_gru, bh_gru,
                                           hidB,
                                           efp, rp, W_edge, b_edge, row_ptr,
                                           tmpB);
    // gru1 + msg2
    k_fused<<<grid_blk, b256, 0, stream>>>(hidB, tmpB, rrow_ptr,
                                           Wi_gru, Wh_gru, bi_gru, bh_gru,
                                           hidA,
                                           efp, rp, W_edge, b_edge, row_ptr,
                                           tmpA);
    // gru2 + readout (hn stays in registers)
    k_gru_red<<<grid_n16, b256, 0, stream>>>(hidA, tmpA, rrow_ptr,
                                             Wi_gru, Wh_gru, bi_gru, bh_gru,
                                             hidden0,
                                             W_ri, b_ri, W_rj, b_rj, out);
}